// Round 6
// baseline (385.423 us; speedup 1.0000x reference)
//
#include <hip/hip_runtime.h>
#include <math.h>

#define N_USER 100000
#define N_ITEM 50000
#define N_EDGE 800000
#define D_IN 256
#define D_H 128
#define HEADS 4

typedef __attribute__((ext_vector_type(8))) short short8v;   // 8 bf16 (4 VGPR)
typedef __attribute__((ext_vector_type(4))) float f32x4;     // 4 fp32

__device__ __forceinline__ unsigned short f2bf(float x) {    // RNE f32->bf16
  unsigned u = __float_as_uint(x);
  return (unsigned short)((u + 0x7FFFu + ((u >> 16) & 1u)) >> 16);
}
__device__ __forceinline__ float bf2f(unsigned short h) {
  return __uint_as_float((unsigned)h << 16);
}
__device__ __forceinline__ f32x4 splat4(float x) { return (f32x4){x, x, x, x}; }

// ---------------------------------------------------------------------------
// CSR row offsets, edge-parallel run writes (each rs[i] written exactly once).
// ---------------------------------------------------------------------------
__global__ void row_offsets_kernel(const int* __restrict__ dst, int n_edge,
                                   int* __restrict__ rs, int n_dst) {
  int e = blockIdx.x * blockDim.x + threadIdx.x;
  if (e >= n_edge) return;
  int d = dst[e];
  int dprev = (e == 0) ? -1 : dst[e - 1];
  for (int i = dprev + 1; i <= d; ++i) rs[i] = e;
  if (e == n_edge - 1)
    for (int i = d + 1; i <= n_dst; ++i) rs[i] = n_edge;
}

// ---------------------------------------------------------------------------
// One-time W prep: W[256][128] fp32 -> Wt_hi/Wt_lo[128][256] bf16, k permuted
// to the MFMA fragment slot order: slot (kb=lane>>4, j) holds
// k = kb*4 + (j&3) + 16*(j>>2); stored at [n][kbase + kb*8 + j].
// Makes each B fragment a single contiguous 16B global load (L2-resident).
// ---------------------------------------------------------------------------
__global__ __launch_bounds__(256) void wt_prep_kernel(
    const float* __restrict__ W, unsigned short* __restrict__ WtHi,
    unsigned short* __restrict__ WtLo) {
  int tid = blockIdx.x * blockDim.x + threadIdx.x;
  if (tid >= D_IN * D_H) return;
  int n = tid & 127, k = tid >> 7;
  float x = W[(size_t)k * D_H + n];
  unsigned short h = f2bf(x);
  unsigned short l = f2bf(x - bf2f(h));
  int kk = k & 31, kbase = k & ~31;
  int pos = (kk < 16) ? ((kk >> 2) * 8 + (kk & 3))
                      : (((kk - 16) >> 2) * 8 + 4 + (kk & 3));
  WtHi[(size_t)n * D_IN + kbase + pos] = h;
  WtLo[(size_t)n * D_IN + kbase + pos] = l;
}

// ---------------------------------------------------------------------------
// C[M,128] = A[M,256] @ W[256,128] + bias via split-bf16 MFMA
// (Ah*Wh + Ah*Wl + Al*Wh, fp32 accumulate). BARRIER-FREE / LDS-FREE:
// A fragments loaded straight from global (2 float4 per m-frag per k-block,
// bf16-split in registers); B fragments are 16B loads from the slot-ordered
// Wt arrays (128KB -> L2-resident). Waves run fully independently.
// Block 256 thr = 4 waves; wave owns 32 rows (2 m-frags); 8 n-frags.
// C/D layout (verified m89): col = lane&15, row = (lane>>4)*4 + reg.
// ---------------------------------------------------------------------------
__global__ __launch_bounds__(256) void gemm_mfma_kernel(
    const float* __restrict__ A, const unsigned short* __restrict__ WtHi,
    const unsigned short* __restrict__ WtLo, const float* __restrict__ bias,
    float* __restrict__ C, int M) {
  const int t = threadIdx.x;
  const int wave = t >> 6, lane = t & 63;
  const int l15 = lane & 15, kb = lane >> 4;
  const int m0 = blockIdx.x * 128 + wave * 32;
  const int r0 = m0 + l15, r1 = m0 + 16 + l15;
  const bool v0 = r0 < M, v1 = r1 < M;
  const float* arow0 = A + (size_t)r0 * D_IN + kb * 4;
  const float* arow1 = A + (size_t)r1 * D_IN + kb * 4;
  const unsigned short* bh_base = WtHi + (size_t)l15 * D_IN + kb * 8;
  const unsigned short* bl_base = WtLo + (size_t)l15 * D_IN + kb * 8;

  f32x4 acc[2][8];
#pragma unroll
  for (int mf = 0; mf < 2; ++mf)
#pragma unroll
    for (int nf = 0; nf < 8; ++nf) acc[mf][nf] = (f32x4){0.f, 0.f, 0.f, 0.f};

#pragma unroll 2
  for (int k0 = 0; k0 < D_IN; k0 += 32) {
    // A fragments direct from global: slots j=0..3 <- k=kb*4+j, j=4..7 <- +16
    float4 a00 = make_float4(0, 0, 0, 0), a01 = a00, a10 = a00, a11 = a00;
    if (v0) {
      a00 = *(const float4*)(arow0 + k0);
      a01 = *(const float4*)(arow0 + k0 + 16);
    }
    if (v1) {
      a10 = *(const float4*)(arow1 + k0);
      a11 = *(const float4*)(arow1 + k0 + 16);
    }
    short8v ah0, al0, ah1, al1;
    {
      const float e0[8] = {a00.x, a00.y, a00.z, a00.w, a01.x, a01.y, a01.z, a01.w};
      const float e1[8] = {a10.x, a10.y, a10.z, a10.w, a11.x, a11.y, a11.z, a11.w};
#pragma unroll
      for (int j = 0; j < 8; ++j) {
        unsigned short h0 = f2bf(e0[j]); ah0[j] = (short)h0;
        al0[j] = (short)f2bf(e0[j] - bf2f(h0));
        unsigned short h1 = f2bf(e1[j]); ah1[j] = (short)h1;
        al1[j] = (short)f2bf(e1[j] - bf2f(h1));
      }
    }
#pragma unroll
    for (int nf = 0; nf < 8; ++nf) {
      short8v bh = *(const short8v*)(bh_base + (size_t)nf * 16 * D_IN + k0);
      short8v bl = *(const short8v*)(bl_base + (size_t)nf * 16 * D_IN + k0);
      acc[0][nf] = __builtin_amdgcn_mfma_f32_16x16x32_bf16(ah0, bh, acc[0][nf], 0, 0, 0);
      acc[0][nf] = __builtin_amdgcn_mfma_f32_16x16x32_bf16(ah0, bl, acc[0][nf], 0, 0, 0);
      acc[0][nf] = __builtin_amdgcn_mfma_f32_16x16x32_bf16(al0, bh, acc[0][nf], 0, 0, 0);
      acc[1][nf] = __builtin_amdgcn_mfma_f32_16x16x32_bf16(ah1, bh, acc[1][nf], 0, 0, 0);
      acc[1][nf] = __builtin_amdgcn_mfma_f32_16x16x32_bf16(ah1, bl, acc[1][nf], 0, 0, 0);
      acc[1][nf] = __builtin_amdgcn_mfma_f32_16x16x32_bf16(al1, bh, acc[1][nf], 0, 0, 0);
    }
  }

#pragma unroll
  for (int nf = 0; nf < 8; ++nf) {
    float bv = bias[nf * 16 + l15];
#pragma unroll
    for (int mf = 0; mf < 2; ++mf) {
#pragma unroll
      for (int r = 0; r < 4; ++r) {
        int grow = m0 + mf * 16 + kb * 4 + r;
        if (grow < M) C[(size_t)grow * D_H + nf * 16 + l15] = acc[mf][nf][r] + bv;
      }
    }
  }
}

// ---------------------------------------------------------------------------
// s[n,4] = C[n,128] @ a[4,128]^T  (one wave per row; optional second a)
// ---------------------------------------------------------------------------
__global__ __launch_bounds__(256) void scores_kernel(
    const float* __restrict__ C, int n,
    const float* __restrict__ a0, float* __restrict__ s0,
    const float* __restrict__ a1, float* __restrict__ s1) {
  int wid = (blockIdx.x * blockDim.x + threadIdx.x) >> 6;
  int lane = threadIdx.x & 63;
  if (wid >= n) return;
  float2 v = *(const float2*)&C[(size_t)wid * D_H + lane * 2];
#pragma unroll
  for (int h = 0; h < HEADS; ++h) {
    float p = v.x * a0[h * D_H + lane * 2] + v.y * a0[h * D_H + lane * 2 + 1];
#pragma unroll
    for (int off = 32; off; off >>= 1) p += __shfl_xor(p, off);
    if (lane == 0) s0[wid * HEADS + h] = p;
  }
  if (a1) {
#pragma unroll
    for (int h = 0; h < HEADS; ++h) {
      float p = v.x * a1[h * D_H + lane * 2] + v.y * a1[h * D_H + lane * 2 + 1];
#pragma unroll
      for (int off = 32; off; off >>= 1) p += __shfl_xor(p, off);
      if (lane == 0) s1[wid * HEADS + h] = p;
    }
  }
}

// ---------------------------------------------------------------------------
// Per-edge UNNORMALIZED weights w = exp(leaky_relu(s_src+s_dst)).
// ---------------------------------------------------------------------------
__global__ __launch_bounds__(256) void edge_w_kernel(
    const float* __restrict__ s_src, const float* __restrict__ s_dst,
    const int* __restrict__ src_idx, const int* __restrict__ dst_idx,
    float* __restrict__ wout, int n_edge) {
  int e = blockIdx.x * blockDim.x + threadIdx.x;
  if (e >= n_edge) return;
  int s = src_idx[e], d = dst_idx[e];
  f32x4 a = *(const f32x4*)&s_src[(size_t)s * HEADS];
  f32x4 b = *(const f32x4*)&s_dst[(size_t)d * HEADS];
  f32x4 v = a + b;
  v.x = (v.x >= 0.f) ? v.x : 0.2f * v.x;
  v.y = (v.y >= 0.f) ? v.y : 0.2f * v.y;
  v.z = (v.z >= 0.f) ? v.z : 0.2f * v.z;
  v.w = (v.w >= 0.f) ? v.w : 0.2f * v.w;
  f32x4 w = {__expf(v.x), __expf(v.y), __expf(v.z), __expf(v.w)};
  *(f32x4*)&wout[(size_t)e * HEADS] = w;
}

// ---------------------------------------------------------------------------
// Weighted gather-sum + in-loop denominator. One wave per dst;
// lanes = 2 edge-slots x 32 dim-groups (float4). Packed f32x4 math.
// ---------------------------------------------------------------------------
__global__ __launch_bounds__(256) void attend_sum_kernel(
    const float* __restrict__ h_src, const float* __restrict__ w4,
    const int* __restrict__ src_idx, const int* __restrict__ rs,
    float* __restrict__ out, int n_dst,
    const float* __restrict__ a_next, float* __restrict__ s_out) {
  int wid = (blockIdx.x * blockDim.x + threadIdx.x) >> 6;
  int lane = threadIdx.x & 63;
  if (wid >= n_dst) return;
  const int el = lane >> 5;
  const int dl = lane & 31;
  int e0 = rs[wid], e1 = rs[wid + 1];

  f32x4 acc0 = {0, 0, 0, 0}, acc1 = acc0, acc2 = acc0, acc3 = acc0;
  f32x4 den = {0, 0, 0, 0};

  int base = e0;
  for (; base + 4 <= e1; base += 4) {
    int eA = base + el, eB = base + 2 + el;
    int sA = src_idx[eA], sB = src_idx[eB];
    f32x4 hA = *(const f32x4*)&h_src[(size_t)sA * D_H + dl * 4];
    f32x4 hB = *(const f32x4*)&h_src[(size_t)sB * D_H + dl * 4];
    f32x4 wA = *(const f32x4*)&w4[(size_t)eA * HEADS];
    f32x4 wB = *(const f32x4*)&w4[(size_t)eB * HEADS];
    den += wA; den += wB;
    acc0 = __builtin_elementwise_fma(splat4(wA.x), hA, acc0);
    acc1 = __builtin_elementwise_fma(splat4(wA.y), hA, acc1);
    acc2 = __builtin_elementwise_fma(splat4(wA.z), hA, acc2);
    acc3 = __builtin_elementwise_fma(splat4(wA.w), hA, acc3);
    acc0 = __builtin_elementwise_fma(splat4(wB.x), hB, acc0);
    acc1 = __builtin_elementwise_fma(splat4(wB.y), hB, acc1);
    acc2 = __builtin_elementwise_fma(splat4(wB.z), hB, acc2);
    acc3 = __builtin_elementwise_fma(splat4(wB.w), hB, acc3);
  }
  for (; base < e1; base += 2) {
    int e = base + el;
    bool valid = e < e1;
    int ec = valid ? e : e1 - 1;
    int s = src_idx[ec];
    f32x4 hv = *(const f32x4*)&h_src[(size_t)s * D_H + dl * 4];
    f32x4 wv = *(const f32x4*)&w4[(size_t)ec * HEADS];
    if (!valid) wv = (f32x4){0, 0, 0, 0};
    den += wv;
    acc0 = __builtin_elementwise_fma(splat4(wv.x), hv, acc0);
    acc1 = __builtin_elementwise_fma(splat4(wv.y), hv, acc1);
    acc2 = __builtin_elementwise_fma(splat4(wv.z), hv, acc2);
    acc3 = __builtin_elementwise_fma(splat4(wv.w), hv, acc3);
  }

#define MRG(a) \
  a.x += __shfl_xor(a.x, 32); a.y += __shfl_xor(a.y, 32); \
  a.z += __shfl_xor(a.z, 32); a.w += __shfl_xor(a.w, 32);
  MRG(acc0) MRG(acc1) MRG(acc2) MRG(acc3) MRG(den)
#undef MRG

  float r0 = den.x > 0.f ? 1.f / den.x : 0.f;
  float r1 = den.y > 0.f ? 1.f / den.y : 0.f;
  float r2 = den.z > 0.f ? 1.f / den.z : 0.f;
  float r3 = den.w > 0.f ? 1.f / den.w : 0.f;
  acc0 *= splat4(r0); acc1 *= splat4(r1); acc2 *= splat4(r2); acc3 *= splat4(r3);
#define ELU4(a) \
  a.x = (a.x > 0.f) ? a.x : (__expf(a.x) - 1.f); \
  a.y = (a.y > 0.f) ? a.y : (__expf(a.y) - 1.f); \
  a.z = (a.z > 0.f) ? a.z : (__expf(a.z) - 1.f); \
  a.w = (a.w > 0.f) ? a.w : (__expf(a.w) - 1.f);
  ELU4(acc0) ELU4(acc1) ELU4(acc2) ELU4(acc3)
#undef ELU4

  f32x4 o = (acc0 + acc1 + acc2 + acc3) * splat4(0.25f);
  if (el == 0) *(f32x4*)&out[(size_t)wid * D_H + dl * 4] = o;

  if (s_out) {
#pragma unroll
    for (int h = 0; h < HEADS; ++h) {
      const float* ah = &a_next[h * D_H + dl * 4];
      float p = o.x * ah[0] + o.y * ah[1] + o.z * ah[2] + o.w * ah[3];
#pragma unroll
      for (int off = 16; off; off >>= 1) p += __shfl_xor(p, off);
      if (lane == 0) s_out[wid * HEADS + h] = p;
    }
  }
}

// ---------------------------------------------------------------------------
extern "C" void kernel_launch(void* const* d_in, const int* in_sizes, int n_in,
                              void* d_out, int out_size, void* d_ws, size_t ws_size,
                              hipStream_t stream) {
  const float* h_user     = (const float*)d_in[0];
  const float* h_item     = (const float*)d_in[1];
  const float* w_user     = (const float*)d_in[2];
  const float* b_user     = (const float*)d_in[3];
  const float* w_item     = (const float*)d_in[4];
  const float* b_item     = (const float*)d_in[5];
  const float* a_user_src = (const float*)d_in[6];
  const float* a_user_dst = (const float*)d_in[7];
  const float* a_item_src = (const float*)d_in[8];
  const float* a_item_dst = (const float*)d_in[9];
  const int* i2u_src = (const int*)d_in[10];
  const int* i2u_dst = (const int*)d_in[11];
  const int* u2i_src = (const int*)d_in[12];
  const int* u2i_dst = (const int*)d_in[13];

  float* out_user = (float*)d_out;                       // hu_new (N_USER,128)
  float* out_item = out_user + (size_t)N_USER * D_H;     // hi_new (N_ITEM,128)

  // workspace layout
  float* hu      = (float*)d_ws;                         // (N_USER,128) 51.2MB
  float* hi      = hu + (size_t)N_USER * D_H;            // (N_ITEM,128)
  float* s_i_src = hi + (size_t)N_ITEM * D_H;            // (N_ITEM,4)
  float* s_i_dst = s_i_src + (size_t)N_ITEM * HEADS;     // (N_ITEM,4)
  float* s_u_dst = s_i_dst + (size_t)N_ITEM * HEADS;     // (N_USER,4)
  float* s_un    = s_u_dst + (size_t)N_USER * HEADS;     // (N_USER,4)
  int* user_rs = (int*)(s_un + (size_t)N_USER * HEADS);  // N_USER+1
  int* item_rs = user_rs + (N_USER + 1);                 // N_ITEM+1
  unsigned short* wtu_hi = (unsigned short*)
      (((uintptr_t)(item_rs + N_ITEM + 1) + 15) & ~(uintptr_t)15);
  unsigned short* wtu_lo = wtu_hi + (size_t)D_IN * D_H;
  unsigned short* wti_hi = wtu_lo + (size_t)D_IN * D_H;
  unsigned short* wti_lo = wti_hi + (size_t)D_IN * D_H;
  // hu is dead after scores_kernel -> alias edge weight buffer into it
  float* wbuf = hu;                                      // (E,4) 12.8MB

  // CSR offsets (edge-parallel run writes)
  hipLaunchKernelGGL(row_offsets_kernel, dim3((N_EDGE + 255) / 256), dim3(256), 0,
                     stream, i2u_dst, N_EDGE, user_rs, N_USER);
  hipLaunchKernelGGL(row_offsets_kernel, dim3((N_EDGE + 255) / 256), dim3(256), 0,
                     stream, u2i_dst, N_EDGE, item_rs, N_ITEM);

  // W prep + projections (barrier-free split-bf16 MFMA)
  hipLaunchKernelGGL(wt_prep_kernel, dim3(D_IN * D_H / 256), dim3(256), 0, stream,
                     w_user, wtu_hi, wtu_lo);
  hipLaunchKernelGGL(wt_prep_kernel, dim3(D_IN * D_H / 256), dim3(256), 0, stream,
                     w_item, wti_hi, wti_lo);
  hipLaunchKernelGGL(gemm_mfma_kernel, dim3((N_USER + 127) / 128), dim3(256), 0, stream,
                     h_user, wtu_hi, wtu_lo, b_user, hu, N_USER);
  hipLaunchKernelGGL(gemm_mfma_kernel, dim3((N_ITEM + 127) / 128), dim3(256), 0, stream,
                     h_item, wti_hi, wti_lo, b_item, hi, N_ITEM);

  // per-node attention scores
  hipLaunchKernelGGL(scores_kernel, dim3(N_ITEM / 4), dim3(256), 0, stream,
                     hi, N_ITEM, a_user_src, s_i_src, a_item_dst, s_i_dst);
  hipLaunchKernelGGL(scores_kernel, dim3(N_USER / 4), dim3(256), 0, stream,
                     hu, N_USER, a_user_dst, s_u_dst, (const float*)nullptr, (float*)nullptr);

  // ---- layer 1: items -> users ----
  hipLaunchKernelGGL(edge_w_kernel, dim3((N_EDGE + 255) / 256), dim3(256), 0, stream,
                     s_i_src, s_u_dst, i2u_src, i2u_dst, wbuf, N_EDGE);
  hipLaunchKernelGGL(attend_sum_kernel, dim3((N_USER + 3) / 4), dim3(256), 0, stream,
                     hi, wbuf, i2u_src, user_rs, out_user, N_USER,
                     a_item_src, s_un);

  // ---- layer 2: updated users -> items ----
  hipLaunchKernelGGL(edge_w_kernel, dim3((N_EDGE + 255) / 256), dim3(256), 0, stream,
                     s_un, s_i_dst, u2i_src, u2i_dst, wbuf, N_EDGE);
  hipLaunchKernelGGL(attend_sum_kernel, dim3((N_ITEM + 3) / 4), dim3(256), 0, stream,
                     out_user, wbuf, u2i_src, item_rs, out_item, N_ITEM,
                     (const float*)nullptr, (float*)nullptr);
}

// Round 8
// 378.322 us; speedup vs baseline: 1.0188x; 1.0188x over previous
//
#include <hip/hip_runtime.h>
#include <math.h>

#define N_USER 100000
#define N_ITEM 50000
#define N_EDGE 800000
#define D_IN 256
#define D_H 128
#define HEADS 4

typedef __attribute__((ext_vector_type(8))) short short8v;   // 8 bf16 (4 VGPR)
typedef __attribute__((ext_vector_type(4))) float f32x4;     // 4 fp32

__device__ __forceinline__ unsigned short f2bf(float x) {    // RNE f32->bf16
  unsigned u = __float_as_uint(x);
  return (unsigned short)((u + 0x7FFFu + ((u >> 16) & 1u)) >> 16);
}
__device__ __forceinline__ float bf2f(unsigned short h) {
  return __uint_as_float((unsigned)h << 16);
}
__device__ __forceinline__ f32x4 splat4(float x) { return (f32x4){x, x, x, x}; }

// ---------------------------------------------------------------------------
// CSR row offsets, edge-parallel run writes (each rs[i] written exactly once).
// ---------------------------------------------------------------------------
__global__ void row_offsets_kernel(const int* __restrict__ dst, int n_edge,
                                   int* __restrict__ rs, int n_dst) {
  int e = blockIdx.x * blockDim.x + threadIdx.x;
  if (e >= n_edge) return;
  int d = dst[e];
  int dprev = (e == 0) ? -1 : dst[e - 1];
  for (int i = dprev + 1; i <= d; ++i) rs[i] = e;
  if (e == n_edge - 1)
    for (int i = d + 1; i <= n_dst; ++i) rs[i] = n_edge;
}

// ---------------------------------------------------------------------------
// One-time W prep: W[256][128] fp32 -> Wt_hi/Wt_lo[128][256] bf16, k permuted
// to the MFMA fragment slot order: slot (kb=lane>>4, j) holds
// k = kb*4 + (j&3) + 16*(j>>2); stored at [n][kbase + kb*8 + j].
// ---------------------------------------------------------------------------
__global__ __launch_bounds__(256) void wt_prep_kernel(
    const float* __restrict__ W, unsigned short* __restrict__ WtHi,
    unsigned short* __restrict__ WtLo) {
  int tid = blockIdx.x * blockDim.x + threadIdx.x;
  if (tid >= D_IN * D_H) return;
  int n = tid & 127, k = tid >> 7;
  float x = W[(size_t)k * D_H + n];
  unsigned short h = f2bf(x);
  unsigned short l = f2bf(x - bf2f(h));
  int kk = k & 31, kbase = k & ~31;
  int pos = (kk < 16) ? ((kk >> 2) * 8 + (kk & 3))
                      : (((kk - 16) >> 2) * 8 + 4 + (kk & 3));
  WtHi[(size_t)n * D_IN + kbase + pos] = h;
  WtLo[(size_t)n * D_IN + kbase + pos] = l;
}

// ---------------------------------------------------------------------------
// GEMM helpers (inline functions, not macros — round-7 compile fix).
// ---------------------------------------------------------------------------
__device__ __forceinline__ void lda_frag(const float* arow0, const float* arow1,
                                         bool v0, bool v1, int k0,
                                         float4& P0, float4& P1,
                                         float4& P2, float4& P3) {
  const float4 z = make_float4(0.f, 0.f, 0.f, 0.f);
  P0 = z; P1 = z; P2 = z; P3 = z;
  if (v0) { P0 = *(const float4*)(arow0 + k0);
            P1 = *(const float4*)(arow0 + k0 + 16); }
  if (v1) { P2 = *(const float4*)(arow1 + k0);
            P3 = *(const float4*)(arow1 + k0 + 16); }
}

__device__ __forceinline__ void ldb_frag(const unsigned short* bh_base,
                                         const unsigned short* bl_base, int k0,
                                         short8v& H0, short8v& V0, short8v& H1, short8v& V1,
                                         short8v& H2, short8v& V2, short8v& H3, short8v& V3) {
  H0 = *(const short8v*)(bh_base + 0 * 16 * D_IN + k0);
  V0 = *(const short8v*)(bl_base + 0 * 16 * D_IN + k0);
  H1 = *(const short8v*)(bh_base + 1 * 16 * D_IN + k0);
  V1 = *(const short8v*)(bl_base + 1 * 16 * D_IN + k0);
  H2 = *(const short8v*)(bh_base + 2 * 16 * D_IN + k0);
  V2 = *(const short8v*)(bl_base + 2 * 16 * D_IN + k0);
  H3 = *(const short8v*)(bh_base + 3 * 16 * D_IN + k0);
  V3 = *(const short8v*)(bl_base + 3 * 16 * D_IN + k0);
}

__device__ __forceinline__ void mfma_step(
    const float4& P0, const float4& P1, const float4& P2, const float4& P3,
    const short8v& H0, const short8v& V0, const short8v& H1, const short8v& V1,
    const short8v& H2, const short8v& V2, const short8v& H3, const short8v& V3,
    f32x4& acc00, f32x4& acc01, f32x4& acc02, f32x4& acc03,
    f32x4& acc10, f32x4& acc11, f32x4& acc12, f32x4& acc13) {
  short8v ah0, al0, ah1, al1;
  const float e0[8] = {P0.x, P0.y, P0.z, P0.w, P1.x, P1.y, P1.z, P1.w};
  const float e1[8] = {P2.x, P2.y, P2.z, P2.w, P3.x, P3.y, P3.z, P3.w};
#pragma unroll
  for (int j = 0; j < 8; ++j) {
    unsigned short h0 = f2bf(e0[j]); ah0[j] = (short)h0;
    al0[j] = (short)f2bf(e0[j] - bf2f(h0));
    unsigned short h1 = f2bf(e1[j]); ah1[j] = (short)h1;
    al1[j] = (short)f2bf(e1[j] - bf2f(h1));
  }
  acc00 = __builtin_amdgcn_mfma_f32_16x16x32_bf16(ah0, H0, acc00, 0, 0, 0);
  acc00 = __builtin_amdgcn_mfma_f32_16x16x32_bf16(ah0, V0, acc00, 0, 0, 0);
  acc00 = __builtin_amdgcn_mfma_f32_16x16x32_bf16(al0, H0, acc00, 0, 0, 0);
  acc10 = __builtin_amdgcn_mfma_f32_16x16x32_bf16(ah1, H0, acc10, 0, 0, 0);
  acc10 = __builtin_amdgcn_mfma_f32_16x16x32_bf16(ah1, V0, acc10, 0, 0, 0);
  acc10 = __builtin_amdgcn_mfma_f32_16x16x32_bf16(al1, H0, acc10, 0, 0, 0);
  acc01 = __builtin_amdgcn_mfma_f32_16x16x32_bf16(ah0, H1, acc01, 0, 0, 0);
  acc01 = __builtin_amdgcn_mfma_f32_16x16x32_bf16(ah0, V1, acc01, 0, 0, 0);
  acc01 = __builtin_amdgcn_mfma_f32_16x16x32_bf16(al0, H1, acc01, 0, 0, 0);
  acc11 = __builtin_amdgcn_mfma_f32_16x16x32_bf16(ah1, H1, acc11, 0, 0, 0);
  acc11 = __builtin_amdgcn_mfma_f32_16x16x32_bf16(ah1, V1, acc11, 0, 0, 0);
  acc11 = __builtin_amdgcn_mfma_f32_16x16x32_bf16(al1, H1, acc11, 0, 0, 0);
  acc02 = __builtin_amdgcn_mfma_f32_16x16x32_bf16(ah0, H2, acc02, 0, 0, 0);
  acc02 = __builtin_amdgcn_mfma_f32_16x16x32_bf16(ah0, V2, acc02, 0, 0, 0);
  acc02 = __builtin_amdgcn_mfma_f32_16x16x32_bf16(al0, H2, acc02, 0, 0, 0);
  acc12 = __builtin_amdgcn_mfma_f32_16x16x32_bf16(ah1, H2, acc12, 0, 0, 0);
  acc12 = __builtin_amdgcn_mfma_f32_16x16x32_bf16(ah1, V2, acc12, 0, 0, 0);
  acc12 = __builtin_amdgcn_mfma_f32_16x16x32_bf16(al1, H2, acc12, 0, 0, 0);
  acc03 = __builtin_amdgcn_mfma_f32_16x16x32_bf16(ah0, H3, acc03, 0, 0, 0);
  acc03 = __builtin_amdgcn_mfma_f32_16x16x32_bf16(ah0, V3, acc03, 0, 0, 0);
  acc03 = __builtin_amdgcn_mfma_f32_16x16x32_bf16(al0, H3, acc03, 0, 0, 0);
  acc13 = __builtin_amdgcn_mfma_f32_16x16x32_bf16(ah1, H3, acc13, 0, 0, 0);
  acc13 = __builtin_amdgcn_mfma_f32_16x16x32_bf16(ah1, V3, acc13, 0, 0, 0);
  acc13 = __builtin_amdgcn_mfma_f32_16x16x32_bf16(al1, H3, acc13, 0, 0, 0);
}

// ---------------------------------------------------------------------------
// C[M,128] = A[M,256] @ W[256,128] + bias via split-bf16 MFMA
// (Ah*Wh + Ah*Wl + Al*Wh, fp32 accumulate). Barrier-free, LDS-free,
// register double-buffered; launch_bounds(256,2) -> VGPR cap 256
// (round-6 failure: VGPR=80 forced serial load->waitcnt->use).
// Wave tile 32 rows x 64 cols; block covers 128 rows x 64 cols;
// grid (ceil(M/128), 2). C/D layout: col=lane&15, row=(lane>>4)*4+reg.
// ---------------------------------------------------------------------------
__global__ __launch_bounds__(256, 2) void gemm_mfma_kernel(
    const float* __restrict__ A, const unsigned short* __restrict__ WtHi,
    const unsigned short* __restrict__ WtLo, const float* __restrict__ bias,
    float* __restrict__ C, int M) {
  const int t = threadIdx.x;
  const int wave = t >> 6, lane = t & 63;
  const int l15 = lane & 15, kb = lane >> 4;
  const int m0 = blockIdx.x * 128 + wave * 32;
  const int n0 = blockIdx.y * 64;
  const int r0 = m0 + l15, r1 = m0 + 16 + l15;
  const bool v0 = r0 < M, v1 = r1 < M;
  const float* arow0 = A + (size_t)r0 * D_IN + kb * 4;
  const float* arow1 = A + (size_t)r1 * D_IN + kb * 4;
  const unsigned short* bh_base = WtHi + (size_t)(n0 + l15) * D_IN + kb * 8;
  const unsigned short* bl_base = WtLo + (size_t)(n0 + l15) * D_IN + kb * 8;

  f32x4 acc00 = {0, 0, 0, 0}, acc01 = acc00, acc02 = acc00, acc03 = acc00;
  f32x4 acc10 = acc00, acc11 = acc00, acc12 = acc00, acc13 = acc00;

  float4 pa0, pa1, pa2, pa3, qa0, qa1, qa2, qa3;
  short8v pbh0, pbl0, pbh1, pbl1, pbh2, pbl2, pbh3, pbl3;
  short8v qbh0, qbl0, qbh1, qbl1, qbh2, qbl2, qbh3, qbl3;

  lda_frag(arow0, arow1, v0, v1, 0, pa0, pa1, pa2, pa3);
  ldb_frag(bh_base, bl_base, 0, pbh0, pbl0, pbh1, pbl1, pbh2, pbl2, pbh3, pbl3);

  lda_frag(arow0, arow1, v0, v1, 32, qa0, qa1, qa2, qa3);
  ldb_frag(bh_base, bl_base, 32, qbh0, qbl0, qbh1, qbl1, qbh2, qbl2, qbh3, qbl3);
  mfma_step(pa0, pa1, pa2, pa3, pbh0, pbl0, pbh1, pbl1, pbh2, pbl2, pbh3, pbl3,
            acc00, acc01, acc02, acc03, acc10, acc11, acc12, acc13);

  lda_frag(arow0, arow1, v0, v1, 64, pa0, pa1, pa2, pa3);
  ldb_frag(bh_base, bl_base, 64, pbh0, pbl0, pbh1, pbl1, pbh2, pbl2, pbh3, pbl3);
  mfma_step(qa0, qa1, qa2, qa3, qbh0, qbl0, qbh1, qbl1, qbh2, qbl2, qbh3, qbl3,
            acc00, acc01, acc02, acc03, acc10, acc11, acc12, acc13);

  lda_frag(arow0, arow1, v0, v1, 96, qa0, qa1, qa2, qa3);
  ldb_frag(bh_base, bl_base, 96, qbh0, qbl0, qbh1, qbl1, qbh2, qbl2, qbh3, qbl3);
  mfma_step(pa0, pa1, pa2, pa3, pbh0, pbl0, pbh1, pbl1, pbh2, pbl2, pbh3, pbl3,
            acc00, acc01, acc02, acc03, acc10, acc11, acc12, acc13);

  lda_frag(arow0, arow1, v0, v1, 128, pa0, pa1, pa2, pa3);
  ldb_frag(bh_base, bl_base, 128, pbh0, pbl0, pbh1, pbl1, pbh2, pbl2, pbh3, pbl3);
  mfma_step(qa0, qa1, qa2, qa3, qbh0, qbl0, qbh1, qbl1, qbh2, qbl2, qbh3, qbl3,
            acc00, acc01, acc02, acc03, acc10, acc11, acc12, acc13);

  lda_frag(arow0, arow1, v0, v1, 160, qa0, qa1, qa2, qa3);
  ldb_frag(bh_base, bl_base, 160, qbh0, qbl0, qbh1, qbl1, qbh2, qbl2, qbh3, qbl3);
  mfma_step(pa0, pa1, pa2, pa3, pbh0, pbl0, pbh1, pbl1, pbh2, pbl2, pbh3, pbl3,
            acc00, acc01, acc02, acc03, acc10, acc11, acc12, acc13);

  lda_frag(arow0, arow1, v0, v1, 192, pa0, pa1, pa2, pa3);
  ldb_frag(bh_base, bl_base, 192, pbh0, pbl0, pbh1, pbl1, pbh2, pbl2, pbh3, pbl3);
  mfma_step(qa0, qa1, qa2, qa3, qbh0, qbl0, qbh1, qbl1, qbh2, qbl2, qbh3, qbl3,
            acc00, acc01, acc02, acc03, acc10, acc11, acc12, acc13);

  lda_frag(arow0, arow1, v0, v1, 224, qa0, qa1, qa2, qa3);
  ldb_frag(bh_base, bl_base, 224, qbh0, qbl0, qbh1, qbl1, qbh2, qbl2, qbh3, qbl3);
  mfma_step(pa0, pa1, pa2, pa3, pbh0, pbl0, pbh1, pbl1, pbh2, pbl2, pbh3, pbl3,
            acc00, acc01, acc02, acc03, acc10, acc11, acc12, acc13);

  mfma_step(qa0, qa1, qa2, qa3, qbh0, qbl0, qbh1, qbl1, qbh2, qbl2, qbh3, qbl3,
            acc00, acc01, acc02, acc03, acc10, acc11, acc12, acc13);

  // epilogue
  {
    const f32x4* accs[8] = {&acc00, &acc01, &acc02, &acc03,
                            &acc10, &acc11, &acc12, &acc13};
#pragma unroll
    for (int mf = 0; mf < 2; ++mf) {
#pragma unroll
      for (int nf = 0; nf < 4; ++nf) {
        const f32x4& a = *accs[mf * 4 + nf];
        float bv = bias[n0 + nf * 16 + l15];
#pragma unroll
        for (int r = 0; r < 4; ++r) {
          int grow = m0 + mf * 16 + kb * 4 + r;
          if (grow < M) C[(size_t)grow * D_H + n0 + nf * 16 + l15] = a[r] + bv;
        }
      }
    }
  }
}

// ---------------------------------------------------------------------------
// s[n,4] = C[n,128] @ a[4,128]^T  (one wave per row; optional second a)
// ---------------------------------------------------------------------------
__global__ __launch_bounds__(256) void scores_kernel(
    const float* __restrict__ C, int n,
    const float* __restrict__ a0, float* __restrict__ s0,
    const float* __restrict__ a1, float* __restrict__ s1) {
  int wid = (blockIdx.x * blockDim.x + threadIdx.x) >> 6;
  int lane = threadIdx.x & 63;
  if (wid >= n) return;
  float2 v = *(const float2*)&C[(size_t)wid * D_H + lane * 2];
#pragma unroll
  for (int h = 0; h < HEADS; ++h) {
    float p = v.x * a0[h * D_H + lane * 2] + v.y * a0[h * D_H + lane * 2 + 1];
#pragma unroll
    for (int off = 32; off; off >>= 1) p += __shfl_xor(p, off);
    if (lane == 0) s0[wid * HEADS + h] = p;
  }
  if (a1) {
#pragma unroll
    for (int h = 0; h < HEADS; ++h) {
      float p = v.x * a1[h * D_H + lane * 2] + v.y * a1[h * D_H + lane * 2 + 1];
#pragma unroll
      for (int off = 32; off; off >>= 1) p += __shfl_xor(p, off);
      if (lane == 0) s1[wid * HEADS + h] = p;
    }
  }
}

// ---------------------------------------------------------------------------
// Per-edge UNNORMALIZED weights w = exp(leaky_relu(s_src+s_dst)).
// ---------------------------------------------------------------------------
__global__ __launch_bounds__(256) void edge_w_kernel(
    const float* __restrict__ s_src, const float* __restrict__ s_dst,
    const int* __restrict__ src_idx, const int* __restrict__ dst_idx,
    float* __restrict__ wout, int n_edge) {
  int e = blockIdx.x * blockDim.x + threadIdx.x;
  if (e >= n_edge) return;
  int s = src_idx[e], d = dst_idx[e];
  f32x4 a = *(const f32x4*)&s_src[(size_t)s * HEADS];
  f32x4 b = *(const f32x4*)&s_dst[(size_t)d * HEADS];
  f32x4 v = a + b;
  v.x = (v.x >= 0.f) ? v.x : 0.2f * v.x;
  v.y = (v.y >= 0.f) ? v.y : 0.2f * v.y;
  v.z = (v.z >= 0.f) ? v.z : 0.2f * v.z;
  v.w = (v.w >= 0.f) ? v.w : 0.2f * v.w;
  f32x4 w = {__expf(v.x), __expf(v.y), __expf(v.z), __expf(v.w)};
  *(f32x4*)&wout[(size_t)e * HEADS] = w;
}

// ---------------------------------------------------------------------------
// Weighted gather-sum + in-loop denominator. One wave per dst;
// lanes = 2 edge-slots x 32 dim-groups (float4). Packed f32x4 math.
// Epilogue: rcp (not div); ELU split across half-waves (8 elem/lane not 16).
// ---------------------------------------------------------------------------
__global__ __launch_bounds__(256) void attend_sum_kernel(
    const float* __restrict__ h_src, const float* __restrict__ w4,
    const int* __restrict__ src_idx, const int* __restrict__ rs,
    float* __restrict__ out, int n_dst,
    const float* __restrict__ a_next, float* __restrict__ s_out) {
  int wid = (blockIdx.x * blockDim.x + threadIdx.x) >> 6;
  int lane = threadIdx.x & 63;
  if (wid >= n_dst) return;
  const int el = lane >> 5;
  const int dl = lane & 31;
  int e0 = rs[wid], e1 = rs[wid + 1];

  f32x4 acc0 = {0, 0, 0, 0}, acc1 = acc0, acc2 = acc0, acc3 = acc0;
  f32x4 den = {0, 0, 0, 0};

  int base = e0;
  for (; base + 4 <= e1; base += 4) {
    int eA = base + el, eB = base + 2 + el;
    int sA = src_idx[eA], sB = src_idx[eB];
    f32x4 hA = *(const f32x4*)&h_src[(size_t)sA * D_H + dl * 4];
    f32x4 hB = *(const f32x4*)&h_src[(size_t)sB * D_H + dl * 4];
    f32x4 wA = *(const f32x4*)&w4[(size_t)eA * HEADS];
    f32x4 wB = *(const f32x4*)&w4[(size_t)eB * HEADS];
    den += wA; den += wB;
    acc0 = __builtin_elementwise_fma(splat4(wA.x), hA, acc0);
    acc1 = __builtin_elementwise_fma(splat4(wA.y), hA, acc1);
    acc2 = __builtin_elementwise_fma(splat4(wA.z), hA, acc2);
    acc3 = __builtin_elementwise_fma(splat4(wA.w), hA, acc3);
    acc0 = __builtin_elementwise_fma(splat4(wB.x), hB, acc0);
    acc1 = __builtin_elementwise_fma(splat4(wB.y), hB, acc1);
    acc2 = __builtin_elementwise_fma(splat4(wB.z), hB, acc2);
    acc3 = __builtin_elementwise_fma(splat4(wB.w), hB, acc3);
  }
  for (; base < e1; base += 2) {
    int e = base + el;
    bool valid = e < e1;
    int ec = valid ? e : e1 - 1;
    int s = src_idx[ec];
    f32x4 hv = *(const f32x4*)&h_src[(size_t)s * D_H + dl * 4];
    f32x4 wv = *(const f32x4*)&w4[(size_t)ec * HEADS];
    if (!valid) wv = (f32x4){0, 0, 0, 0};
    den += wv;
    acc0 = __builtin_elementwise_fma(splat4(wv.x), hv, acc0);
    acc1 = __builtin_elementwise_fma(splat4(wv.y), hv, acc1);
    acc2 = __builtin_elementwise_fma(splat4(wv.z), hv, acc2);
    acc3 = __builtin_elementwise_fma(splat4(wv.w), hv, acc3);
  }

#define MRG(a) \
  a.x += __shfl_xor(a.x, 32); a.y += __shfl_xor(a.y, 32); \
  a.z += __shfl_xor(a.z, 32); a.w += __shfl_xor(a.w, 32);
  MRG(acc0) MRG(acc1) MRG(acc2) MRG(acc3) MRG(den)
#undef MRG

  float rA = den.x > 0.f ? __builtin_amdgcn_rcpf(den.x) : 0.f;
  float rB = den.y > 0.f ? __builtin_amdgcn_rcpf(den.y) : 0.f;
  float rC = den.z > 0.f ? __builtin_amdgcn_rcpf(den.z) : 0.f;
  float rD = den.w > 0.f ? __builtin_amdgcn_rcpf(den.w) : 0.f;

  // split ELU work: el=0 handles heads 0,1; el=1 handles heads 2,3
  f32x4 p = el ? acc2 : acc0;
  f32x4 q = el ? acc3 : acc1;
  float rp = el ? rC : rA;
  float rq = el ? rD : rB;
  p *= splat4(rp); q *= splat4(rq);
#define ELU4(a) \
  a.x = (a.x > 0.f) ? a.x : (__expf(a.x) - 1.f); \
  a.y = (a.y > 0.f) ? a.y : (__expf(a.y) - 1.f); \
  a.z = (a.z > 0.f) ? a.z : (__expf(a.z) - 1.f); \
  a.w = (a.w > 0.f) ? a.w : (__expf(a.w) - 1.f);
  ELU4(p) ELU4(q)
#undef ELU4
  f32x4 s4 = p + q;                    // partial 2-head sum per half
  s4.x += __shfl_xor(s4.x, 32);        // combine halves -> full 4-head sum
  s4.y += __shfl_xor(s4.y, 32);
  s4.z += __shfl_xor(s4.z, 32);
  s4.w += __shfl_xor(s4.w, 32);
  f32x4 o = s4 * splat4(0.25f);

  if (el == 0) *(f32x4*)&out[(size_t)wid * D_H + dl * 4] = o;

  if (s_out) {
#pragma unroll
    for (int h = 0; h < HEADS; ++h) {
      const float* ah = &a_next[h * D_H + dl * 4];
      float p2 = o.x * ah[0] + o.y * ah[1] + o.z * ah[2] + o.w * ah[3];
#pragma unroll
      for (int off = 16; off; off >>= 1) p2 += __shfl_xor(p2, off);
      if (lane == 0) s_out[wid * HEADS + h] = p2;
    }
  }
}

// ---------------------------------------------------------------------------
extern "C" void kernel_launch(void* const* d_in, const int* in_sizes, int n_in,
                              void* d_out, int out_size, void* d_ws, size_t ws_size,
                              hipStream_t stream) {
  const float* h_user     = (const float*)d_in[0];
  const float* h_item     = (const float*)d_in[1];
  const float* w_user     = (const float*)d_in[2];
  const float* b_user     = (const float*)d_in[3];
  const float* w_item     = (const float*)d_in[4];
  const float* b_item     = (const float*)d_in[5];
  const float* a_user_src = (const float*)d_in[6];
  const float* a_user_dst = (const float*)d_in[7];
  const float* a_item_src = (const float*)d_in[8];
  const float* a_item_dst = (const float*)d_in[9];
  const int* i2u_src = (const int*)d_in[10];
  const int* i2u_dst = (const int*)d_in[11];
  const int* u2i_src = (const int*)d_in[12];
  const int* u2i_dst = (const int*)d_in[13];

  float* out_user = (float*)d_out;                       // hu_new (N_USER,128)
  float* out_item = out_user + (size_t)N_USER * D_H;     // hi_new (N_ITEM,128)

  // workspace layout
  float* hu      = (float*)d_ws;                         // (N_USER,128) 51.2MB
  float* hi      = hu + (size_t)N_USER * D_H;            // (N_ITEM,128)
  float* s_i_src = hi + (size_t)N_ITEM * D_H;            // (N_ITEM,4)
  float* s_i_dst = s_i_src + (size_t)N_ITEM * HEADS;     // (N_ITEM,4)
  float* s_u_dst = s_i_dst + (size_t)N_ITEM * HEADS;     // (N_USER,4)
  float* s_un    = s_u_dst + (size_t)N_USER * HEADS;     // (N_USER,4)
  int* user_rs = (int*)(s_un + (size_t)N_USER * HEADS);  // N_USER+1
  int* item_rs = user_rs + (N_USER + 1);                 // N_ITEM+1
  unsigned short* wtu_hi = (unsigned short*)
      (((uintptr_t)(item_rs + N_ITEM + 1) + 15) & ~(uintptr_t)15);
  unsigned short* wtu_lo = wtu_hi + (size_t)D_IN * D_H;
  unsigned short* wti_hi = wtu_lo + (size_t)D_IN * D_H;
  unsigned short* wti_lo = wti_hi + (size_t)D_IN * D_H;
  // hu is dead after scores_kernel -> alias edge weight buffer into it
  float* wbuf = hu;                                      // (E,4) 12.8MB

  // CSR offsets (edge-parallel run writes)
  hipLaunchKernelGGL(row_offsets_kernel, dim3((N_EDGE + 255) / 256), dim3(256), 0,
                     stream, i2u_dst, N_EDGE, user_rs, N_USER);
  hipLaunchKernelGGL(row_offsets_kernel, dim3((N_EDGE + 255) / 256), dim3(256), 0,
                     stream, u2i_dst, N_EDGE, item_rs, N_ITEM);

  // W prep + projections (register-double-buffered split-bf16 MFMA)
  hipLaunchKernelGGL(wt_prep_kernel, dim3(D_IN * D_H / 256), dim3(256), 0, stream,
                     w_user, wtu_hi, wtu_lo);
  hipLaunchKernelGGL(wt_prep_kernel, dim3(D_IN * D_H / 256), dim3(256), 0, stream,
                     w_item, wti_hi, wti_lo);
  hipLaunchKernelGGL(gemm_mfma_kernel, dim3((N_USER + 127) / 128, 2), dim3(256), 0, stream,
                     h_user, wtu_hi, wtu_lo, b_user, hu, N_USER);
  hipLaunchKernelGGL(gemm_mfma_kernel, dim3((N_ITEM + 127) / 128, 2), dim3(256), 0, stream,
                     h_item, wti_hi, wti_lo, b_item, hi, N_ITEM);

  // per-node attention scores
  hipLaunchKernelGGL(scores_kernel, dim3(N_ITEM / 4), dim3(256), 0, stream,
                     hi, N_ITEM, a_user_src, s_i_src, a_item_dst, s_i_dst);
  hipLaunchKernelGGL(scores_kernel, dim3(N_USER / 4), dim3(256), 0, stream,
                     hu, N_USER, a_user_dst, s_u_dst, (const float*)nullptr, (float*)nullptr);

  // ---- layer 1: items -> users ----
  hipLaunchKernelGGL(edge_w_kernel, dim3((N_EDGE + 255) / 256), dim3(256), 0, stream,
                     s_i_src, s_u_dst, i2u_src, i2u_dst, wbuf, N_EDGE);
  hipLaunchKernelGGL(attend_sum_kernel, dim3((N_USER + 3) / 4), dim3(256), 0, stream,
                     hi, wbuf, i2u_src, user_rs, out_user, N_USER,
                     a_item_src, s_un);

  // ---- layer 2: updated users -> items ----
  hipLaunchKernelGGL(edge_w_kernel, dim3((N_EDGE + 255) / 256), dim3(256), 0, stream,
                     s_un, s_i_dst, u2i_src, u2i_dst, wbuf, N_EDGE);
  hipLaunchKernelGGL(attend_sum_kernel, dim3((N_ITEM + 3) / 4), dim3(256), 0, stream,
                     out_user, wbuf, u2i_src, item_rs, out_item, N_ITEM,
                     (const float*)nullptr, (float*)nullptr);
}

// Round 9
// 376.172 us; speedup vs baseline: 1.0246x; 1.0057x over previous
//
#include <hip/hip_runtime.h>
#include <math.h>

#define N_USER 100000
#define N_ITEM 50000
#define N_EDGE 800000
#define D_IN 256
#define D_H 128
#define HEADS 4

typedef __attribute__((ext_vector_type(8))) short short8v;   // 8 bf16 (4 VGPR)
typedef __attribute__((ext_vector_type(4))) float f32x4;     // 4 fp32

__device__ __forceinline__ unsigned short f2bf(float x) {    // RNE f32->bf16
  unsigned u = __float_as_uint(x);
  return (unsigned short)((u + 0x7FFFu + ((u >> 16) & 1u)) >> 16);
}
__device__ __forceinline__ float bf2f(unsigned short h) {
  return __uint_as_float((unsigned)h << 16);
}
__device__ __forceinline__ f32x4 splat4(float x) { return (f32x4){x, x, x, x}; }

// ---------------------------------------------------------------------------
// CSR row offsets, edge-parallel run writes (each rs[i] written exactly once).
// ---------------------------------------------------------------------------
__global__ void row_offsets_kernel(const int* __restrict__ dst, int n_edge,
                                   int* __restrict__ rs, int n_dst) {
  int e = blockIdx.x * blockDim.x + threadIdx.x;
  if (e >= n_edge) return;
  int d = dst[e];
  int dprev = (e == 0) ? -1 : dst[e - 1];
  for (int i = dprev + 1; i <= d; ++i) rs[i] = e;
  if (e == n_edge - 1)
    for (int i = d + 1; i <= n_dst; ++i) rs[i] = n_edge;
}

// ---------------------------------------------------------------------------
// One-time W prep: W[256][128] fp32 -> Wt_hi/Wt_lo[128][256] bf16, k permuted
// to the MFMA fragment slot order: slot (kb=lane>>4, j) holds
// k = kb*4 + (j&3) + 16*(j>>2); stored at [n][kbase + kb*8 + j].
// ---------------------------------------------------------------------------
__global__ __launch_bounds__(256) void wt_prep_kernel(
    const float* __restrict__ W, unsigned short* __restrict__ WtHi,
    unsigned short* __restrict__ WtLo) {
  int tid = blockIdx.x * blockDim.x + threadIdx.x;
  if (tid >= D_IN * D_H) return;
  int n = tid & 127, k = tid >> 7;
  float x = W[(size_t)k * D_H + n];
  unsigned short h = f2bf(x);
  unsigned short l = f2bf(x - bf2f(h));
  int kk = k & 31, kbase = k & ~31;
  int pos = (kk < 16) ? ((kk >> 2) * 8 + (kk & 3))
                      : (((kk - 16) >> 2) * 8 + 4 + (kk & 3));
  WtHi[(size_t)n * D_IN + kbase + pos] = h;
  WtLo[(size_t)n * D_IN + kbase + pos] = l;
}

// ---------------------------------------------------------------------------
// C[M,128] = A[M,256] @ W[256,128] + bias via split-bf16 MFMA
// (Ah*Wh + Ah*Wl + Al*Wh, fp32 accumulate).
// m97-pattern: A tile (fp32, 128x64 = 32KB) staged via global_load_lds w=16
// (DMA, no dest VGPRs -> compiler cannot sink the loads; r6/r8 failure mode).
// fp32->bf16 conversion on the consumer side (ds_read->cvt->MFMA).
// LDS bank-conflict fix: XOR-swizzle 16B units (unit ^= row&7) applied to the
// GLOBAL source address (linear LDS dest per m104) and to the ds_read addr.
// B frags direct from L2 (slot-ordered Wt). Full N=128 per block -> A read
// once. BK=64 -> 4 K-steps x 2 barriers. 32KB LDS -> ~3 blocks/CU.
// C/D layout (verified m89): col = lane&15, row = (lane>>4)*4 + reg.
// ---------------------------------------------------------------------------
__global__ __launch_bounds__(256, 3) void gemm_mfma_kernel(
    const float* __restrict__ A, const unsigned short* __restrict__ WtHi,
    const unsigned short* __restrict__ WtLo, const float* __restrict__ bias,
    float* __restrict__ C, int M) {
  __shared__ float Atile[128 * 64];                    // 32 KB
  const int t = threadIdx.x;
  const int wave = t >> 6, lane = t & 63;
  const int l15 = lane & 15, kb = lane >> 4;
  const int m0 = blockIdx.x * 128;
  const unsigned short* bh_base = WtHi + (size_t)l15 * D_IN + kb * 8;
  const unsigned short* bl_base = WtLo + (size_t)l15 * D_IN + kb * 8;

  f32x4 acc[2][8];
#pragma unroll
  for (int mf = 0; mf < 2; ++mf)
#pragma unroll
    for (int nf = 0; nf < 8; ++nf) acc[mf][nf] = (f32x4){0.f, 0.f, 0.f, 0.f};

  for (int k0 = 0; k0 < D_IN; k0 += 64) {
    // ---- stage A tile 128x64 fp32 via global_load_lds (8 instrs/wave) ----
#pragma unroll
    for (int i = 0; i < 8; ++i) {
      int rloc = wave * 32 + i * 4 + (lane >> 4);      // tile row this lane feeds
      int gr = m0 + rloc; if (gr >= M) gr = M - 1;     // clamp (unstored rows)
      int u = (lane & 15) ^ (rloc & 7);                // pre-swizzled 16B unit
      const float* src = A + (size_t)gr * D_IN + k0 + u * 4;
      char* dst = (char*)Atile + (size_t)(wave * 32 + i * 4) * 256;  // wave-uniform
      __builtin_amdgcn_global_load_lds(
          (const __attribute__((address_space(1))) unsigned int*)src,
          (__attribute__((address_space(3))) unsigned int*)dst, 16, 0, 0);
    }
    __syncthreads();

    // ---- compute: 2 k-frags of 32 ----
#pragma unroll
    for (int kf = 0; kf < 2; ++kf) {
      short8v ah[2], al[2];
#pragma unroll
      for (int mf = 0; mf < 2; ++mf) {
        int row = wave * 32 + mf * 16 + l15;
        int u0 = (kf * 8 + kb) ^ (row & 7);            // k = kb*4+0..3
        int u1 = (kf * 8 + kb + 4) ^ (row & 7);        // k = kb*4+16..19
        float4 f0 = *(const float4*)((const char*)Atile + (size_t)row * 256 + u0 * 16);
        float4 f1 = *(const float4*)((const char*)Atile + (size_t)row * 256 + u1 * 16);
        const float e[8] = {f0.x, f0.y, f0.z, f0.w, f1.x, f1.y, f1.z, f1.w};
#pragma unroll
        for (int j = 0; j < 8; ++j) {
          unsigned short h = f2bf(e[j]);
          ah[mf][j] = (short)h;
          al[mf][j] = (short)f2bf(e[j] - bf2f(h));
        }
      }
      const int kk = k0 + kf * 32;
#pragma unroll
      for (int nf = 0; nf < 8; ++nf) {
        short8v bh = *(const short8v*)(bh_base + (size_t)nf * 16 * D_IN + kk);
        short8v bl = *(const short8v*)(bl_base + (size_t)nf * 16 * D_IN + kk);
#pragma unroll
        for (int mf = 0; mf < 2; ++mf) {
          acc[mf][nf] = __builtin_amdgcn_mfma_f32_16x16x32_bf16(ah[mf], bh, acc[mf][nf], 0, 0, 0);
          acc[mf][nf] = __builtin_amdgcn_mfma_f32_16x16x32_bf16(ah[mf], bl, acc[mf][nf], 0, 0, 0);
          acc[mf][nf] = __builtin_amdgcn_mfma_f32_16x16x32_bf16(al[mf], bh, acc[mf][nf], 0, 0, 0);
        }
      }
    }
    __syncthreads();
  }

  // ---- epilogue ----
#pragma unroll
  for (int nf = 0; nf < 8; ++nf) {
    float bv = bias[nf * 16 + l15];
#pragma unroll
    for (int mf = 0; mf < 2; ++mf) {
#pragma unroll
      for (int r = 0; r < 4; ++r) {
        int grow = m0 + wave * 32 + mf * 16 + kb * 4 + r;
        if (grow < M) C[(size_t)grow * D_H + nf * 16 + l15] = acc[mf][nf][r] + bv;
      }
    }
  }
}

// ---------------------------------------------------------------------------
// s[n,4] = C[n,128] @ a[4,128]^T  (one wave per row; optional second a)
// ---------------------------------------------------------------------------
__global__ __launch_bounds__(256) void scores_kernel(
    const float* __restrict__ C, int n,
    const float* __restrict__ a0, float* __restrict__ s0,
    const float* __restrict__ a1, float* __restrict__ s1) {
  int wid = (blockIdx.x * blockDim.x + threadIdx.x) >> 6;
  int lane = threadIdx.x & 63;
  if (wid >= n) return;
  float2 v = *(const float2*)&C[(size_t)wid * D_H + lane * 2];
#pragma unroll
  for (int h = 0; h < HEADS; ++h) {
    float p = v.x * a0[h * D_H + lane * 2] + v.y * a0[h * D_H + lane * 2 + 1];
#pragma unroll
    for (int off = 32; off; off >>= 1) p += __shfl_xor(p, off);
    if (lane == 0) s0[wid * HEADS + h] = p;
  }
  if (a1) {
#pragma unroll
    for (int h = 0; h < HEADS; ++h) {
      float p = v.x * a1[h * D_H + lane * 2] + v.y * a1[h * D_H + lane * 2 + 1];
#pragma unroll
      for (int off = 32; off; off >>= 1) p += __shfl_xor(p, off);
      if (lane == 0) s1[wid * HEADS + h] = p;
    }
  }
}

// ---------------------------------------------------------------------------
// Per-edge UNNORMALIZED weights w = exp(leaky_relu(s_src+s_dst)).
// ---------------------------------------------------------------------------
__global__ __launch_bounds__(256) void edge_w_kernel(
    const float* __restrict__ s_src, const float* __restrict__ s_dst,
    const int* __restrict__ src_idx, const int* __restrict__ dst_idx,
    float* __restrict__ wout, int n_edge) {
  int e = blockIdx.x * blockDim.x + threadIdx.x;
  if (e >= n_edge) return;
  int s = src_idx[e], d = dst_idx[e];
  f32x4 a = *(const f32x4*)&s_src[(size_t)s * HEADS];
  f32x4 b = *(const f32x4*)&s_dst[(size_t)d * HEADS];
  f32x4 v = a + b;
  v.x = (v.x >= 0.f) ? v.x : 0.2f * v.x;
  v.y = (v.y >= 0.f) ? v.y : 0.2f * v.y;
  v.z = (v.z >= 0.f) ? v.z : 0.2f * v.z;
  v.w = (v.w >= 0.f) ? v.w : 0.2f * v.w;
  f32x4 w = {__expf(v.x), __expf(v.y), __expf(v.z), __expf(v.w)};
  *(f32x4*)&wout[(size_t)e * HEADS] = w;
}

// ---------------------------------------------------------------------------
// Weighted gather-sum + in-loop denominator. One wave per dst;
// lanes = 2 edge-slots x 32 dim-groups (float4). Packed f32x4 math.
// Epilogue: rcp (not div); ELU split across half-waves.
// ---------------------------------------------------------------------------
__global__ __launch_bounds__(256) void attend_sum_kernel(
    const float* __restrict__ h_src, const float* __restrict__ w4,
    const int* __restrict__ src_idx, const int* __restrict__ rs,
    float* __restrict__ out, int n_dst,
    const float* __restrict__ a_next, float* __restrict__ s_out) {
  int wid = (blockIdx.x * blockDim.x + threadIdx.x) >> 6;
  int lane = threadIdx.x & 63;
  if (wid >= n_dst) return;
  const int el = lane >> 5;
  const int dl = lane & 31;
  int e0 = rs[wid], e1 = rs[wid + 1];

  f32x4 acc0 = {0, 0, 0, 0}, acc1 = acc0, acc2 = acc0, acc3 = acc0;
  f32x4 den = {0, 0, 0, 0};

  int base = e0;
  for (; base + 4 <= e1; base += 4) {
    int eA = base + el, eB = base + 2 + el;
    int sA = src_idx[eA], sB = src_idx[eB];
    f32x4 hA = *(const f32x4*)&h_src[(size_t)sA * D_H + dl * 4];
    f32x4 hB = *(const f32x4*)&h_src[(size_t)sB * D_H + dl * 4];
    f32x4 wA = *(const f32x4*)&w4[(size_t)eA * HEADS];
    f32x4 wB = *(const f32x4*)&w4[(size_t)eB * HEADS];
    den += wA; den += wB;
    acc0 = __builtin_elementwise_fma(splat4(wA.x), hA, acc0);
    acc1 = __builtin_elementwise_fma(splat4(wA.y), hA, acc1);
    acc2 = __builtin_elementwise_fma(splat4(wA.z), hA, acc2);
    acc3 = __builtin_elementwise_fma(splat4(wA.w), hA, acc3);
    acc0 = __builtin_elementwise_fma(splat4(wB.x), hB, acc0);
    acc1 = __builtin_elementwise_fma(splat4(wB.y), hB, acc1);
    acc2 = __builtin_elementwise_fma(splat4(wB.z), hB, acc2);
    acc3 = __builtin_elementwise_fma(splat4(wB.w), hB, acc3);
  }
  for (; base < e1; base += 2) {
    int e = base + el;
    bool valid = e < e1;
    int ec = valid ? e : e1 - 1;
    int s = src_idx[ec];
    f32x4 hv = *(const f32x4*)&h_src[(size_t)s * D_H + dl * 4];
    f32x4 wv = *(const f32x4*)&w4[(size_t)ec * HEADS];
    if (!valid) wv = (f32x4){0, 0, 0, 0};
    den += wv;
    acc0 = __builtin_elementwise_fma(splat4(wv.x), hv, acc0);
    acc1 = __builtin_elementwise_fma(splat4(wv.y), hv, acc1);
    acc2 = __builtin_elementwise_fma(splat4(wv.z), hv, acc2);
    acc3 = __builtin_elementwise_fma(splat4(wv.w), hv, acc3);
  }

#define MRG(a) \
  a.x += __shfl_xor(a.x, 32); a.y += __shfl_xor(a.y, 32); \
  a.z += __shfl_xor(a.z, 32); a.w += __shfl_xor(a.w, 32);
  MRG(acc0) MRG(acc1) MRG(acc2) MRG(acc3) MRG(den)
#undef MRG

  float rA = den.x > 0.f ? __builtin_amdgcn_rcpf(den.x) : 0.f;
  float rB = den.y > 0.f ? __builtin_amdgcn_rcpf(den.y) : 0.f;
  float rC = den.z > 0.f ? __builtin_amdgcn_rcpf(den.z) : 0.f;
  float rD = den.w > 0.f ? __builtin_amdgcn_rcpf(den.w) : 0.f;

  f32x4 p = el ? acc2 : acc0;
  f32x4 q = el ? acc3 : acc1;
  float rp = el ? rC : rA;
  float rq = el ? rD : rB;
  p *= splat4(rp); q *= splat4(rq);
#define ELU4(a) \
  a.x = (a.x > 0.f) ? a.x : (__expf(a.x) - 1.f); \
  a.y = (a.y > 0.f) ? a.y : (__expf(a.y) - 1.f); \
  a.z = (a.z > 0.f) ? a.z : (__expf(a.z) - 1.f); \
  a.w = (a.w > 0.f) ? a.w : (__expf(a.w) - 1.f);
  ELU4(p) ELU4(q)
#undef ELU4
  f32x4 s4 = p + q;
  s4.x += __shfl_xor(s4.x, 32);
  s4.y += __shfl_xor(s4.y, 32);
  s4.z += __shfl_xor(s4.z, 32);
  s4.w += __shfl_xor(s4.w, 32);
  f32x4 o = s4 * splat4(0.25f);

  if (el == 0) *(f32x4*)&out[(size_t)wid * D_H + dl * 4] = o;

  if (s_out) {
#pragma unroll
    for (int h = 0; h < HEADS; ++h) {
      const float* ah = &a_next[h * D_H + dl * 4];
      float p2 = o.x * ah[0] + o.y * ah[1] + o.z * ah[2] + o.w * ah[3];
#pragma unroll
      for (int off = 16; off; off >>= 1) p2 += __shfl_xor(p2, off);
      if (lane == 0) s_out[wid * HEADS + h] = p2;
    }
  }
}

// ---------------------------------------------------------------------------
extern "C" void kernel_launch(void* const* d_in, const int* in_sizes, int n_in,
                              void* d_out, int out_size, void* d_ws, size_t ws_size,
                              hipStream_t stream) {
  const float* h_user     = (const float*)d_in[0];
  const float* h_item     = (const float*)d_in[1];
  const float* w_user     = (const float*)d_in[2];
  const float* b_user     = (const float*)d_in[3];
  const float* w_item     = (const float*)d_in[4];
  const float* b_item     = (const float*)d_in[5];
  const float* a_user_src = (const float*)d_in[6];
  const float* a_user_dst = (const float*)d_in[7];
  const float* a_item_src = (const float*)d_in[8];
  const float* a_item_dst = (const float*)d_in[9];
  const int* i2u_src = (const int*)d_in[10];
  const int* i2u_dst = (const int*)d_in[11];
  const int* u2i_src = (const int*)d_in[12];
  const int* u2i_dst = (const int*)d_in[13];

  float* out_user = (float*)d_out;                       // hu_new (N_USER,128)
  float* out_item = out_user + (size_t)N_USER * D_H;     // hi_new (N_ITEM,128)

  // workspace layout
  float* hu      = (float*)d_ws;                         // (N_USER,128) 51.2MB
  float* hi      = hu + (size_t)N_USER * D_H;            // (N_ITEM,128)
  float* s_i_src = hi + (size_t)N_ITEM * D_H;            // (N_ITEM,4)
  float* s_i_dst = s_i_src + (size_t)N_ITEM * HEADS;     // (N_ITEM,4)
  float* s_u_dst = s_i_dst + (size_t)N_ITEM * HEADS;     // (N_USER,4)
  float* s_un    = s_u_dst + (size_t)N_USER * HEADS;     // (N_USER,4)
  int* user_rs = (int*)(s_un + (size_t)N_USER * HEADS);  // N_USER+1
  int* item_rs = user_rs + (N_USER + 1);                 // N_ITEM+1
  unsigned short* wtu_hi = (unsigned short*)
      (((uintptr_t)(item_rs + N_ITEM + 1) + 15) & ~(uintptr_t)15);
  unsigned short* wtu_lo = wtu_hi + (size_t)D_IN * D_H;
  unsigned short* wti_hi = wtu_lo + (size_t)D_IN * D_H;
  unsigned short* wti_lo = wti_hi + (size_t)D_IN * D_H;
  // hu is dead after scores_kernel -> alias edge weight buffer into it
  float* wbuf = hu;                                      // (E,4) 12.8MB

  // CSR offsets (edge-parallel run writes)
  hipLaunchKernelGGL(row_offsets_kernel, dim3((N_EDGE + 255) / 256), dim3(256), 0,
                     stream, i2u_dst, N_EDGE, user_rs, N_USER);
  hipLaunchKernelGGL(row_offsets_kernel, dim3((N_EDGE + 255) / 256), dim3(256), 0,
                     stream, u2i_dst, N_EDGE, item_rs, N_ITEM);

  // W prep + projections (global_load_lds m97-pattern split-bf16 MFMA)
  hipLaunchKernelGGL(wt_prep_kernel, dim3(D_IN * D_H / 256), dim3(256), 0, stream,
                     w_user, wtu_hi, wtu_lo);
  hipLaunchKernelGGL(wt_prep_kernel, dim3(D_IN * D_H / 256), dim3(256), 0, stream,
                     w_item, wti_hi, wti_lo);
  hipLaunchKernelGGL(gemm_mfma_kernel, dim3((N_USER + 127) / 128), dim3(256), 0, stream,
                     h_user, wtu_hi, wtu_lo, b_user, hu, N_USER);
  hipLaunchKernelGGL(gemm_mfma_kernel, dim3((N_ITEM + 127) / 128), dim3(256), 0, stream,
                     h_item, wti_hi, wti_lo, b_item, hi, N_ITEM);

  // per-node attention scores
  hipLaunchKernelGGL(scores_kernel, dim3(N_ITEM / 4), dim3(256), 0, stream,
                     hi, N_ITEM, a_user_src, s_i_src, a_item_dst, s_i_dst);
  hipLaunchKernelGGL(scores_kernel, dim3(N_USER / 4), dim3(256), 0, stream,
                     hu, N_USER, a_user_dst, s_u_dst, (const float*)nullptr, (float*)nullptr);

  // ---- layer 1: items -> users ----
  hipLaunchKernelGGL(edge_w_kernel, dim3((N_EDGE + 255) / 256), dim3(256), 0, stream,
                     s_i_src, s_u_dst, i2u_src, i2u_dst, wbuf, N_EDGE);
  hipLaunchKernelGGL(attend_sum_kernel, dim3((N_USER + 3) / 4), dim3(256), 0, stream,
                     hi, wbuf, i2u_src, user_rs, out_user, N_USER,
                     a_item_src, s_un);

  // ---- layer 2: updated users -> items ----
  hipLaunchKernelGGL(edge_w_kernel, dim3((N_EDGE + 255) / 256), dim3(256), 0, stream,
                     s_un, s_i_dst, u2i_src, u2i_dst, wbuf, N_EDGE);
  hipLaunchKernelGGL(attend_sum_kernel, dim3((N_ITEM + 3) / 4), dim3(256), 0, stream,
                     out_user, wbuf, u2i_src, item_rs, out_item, N_ITEM,
                     (const float*)nullptr, (float*)nullptr);
}